// Round 9
// baseline (344.651 us; speedup 1.0000x reference)
//
#include <hip/hip_runtime.h>

// ---------------------------------------------------------------------------
// MHA forward, bf16 MFMA pipeline. Round 15 = round-13 (proven 342.6us) +
// the round-14 attn change re-done via BUILTINS: P matrix redistributed
// lane-to-lane on the VALU pipe with __builtin_amdgcn_permlane{32,16}_swap
// (returns {vdst_new, src_new}), replacing the P LDS round-trip (12 of 32
// LDS-pipe instrs per tile per wave; LDS pipe ~66% occupied = attn's largest
// consumer). Mapping (triple-checked vs R10's harness-passing shfl version):
//   swap32(A,B) -> A'={A_lo,B_lo}, B'={A_hi,B_hi}
//   swap16(A',B') -> f0={A'r0,B'r0,A'r2,B'r2}, f2={A'r1,B'r1,A'r3,B'r3}
// Ps deleted: LDS 37.4 -> 18.9 KB.
// GEMMs/converts/XCD swizzles byte-identical to round 13.
// ---------------------------------------------------------------------------

typedef __bf16 bf16;
typedef bf16 bf16x4 __attribute__((ext_vector_type(4)));
typedef bf16 bf16x8 __attribute__((ext_vector_type(8)));
typedef float f32x4 __attribute__((ext_vector_type(4)));
typedef int i32x2 __attribute__((ext_vector_type(2)));
typedef int i32x4 __attribute__((ext_vector_type(4)));
typedef unsigned u32x2 __attribute__((ext_vector_type(2)));

__device__ __forceinline__ void gld_lds16(const void* g, void* l) {
  __builtin_amdgcn_global_load_lds((__attribute__((address_space(1))) void*)g,
                                   (__attribute__((address_space(3))) void*)l,
                                   16, 0, 0);
}

// ---------------------------------------------------------------------------
// Fused converts. Activations: 2,097,152 float4 each -> grid (8192, 3).
__global__ __launch_bounds__(256) void cvt3(const float* __restrict__ a,
                                            const float* __restrict__ b,
                                            const float* __restrict__ c,
                                            bf16* __restrict__ oa,
                                            bf16* __restrict__ ob,
                                            bf16* __restrict__ oc) {
  const int z = blockIdx.y;
  const float* s = (z == 0) ? a : (z == 1) ? b : c;
  bf16* d = (z == 0) ? oa : (z == 1) ? ob : oc;
  const int i = blockIdx.x * 256 + threadIdx.x;
  float4 f = reinterpret_cast<const float4*>(s)[i];
  bf16x4 o = {(bf16)f.x, (bf16)f.y, (bf16)f.z, (bf16)f.w};
  reinterpret_cast<bf16x4*>(d)[i] = o;
}

// Weights: 262,144 float4 each -> grid (1024, 4).
__global__ __launch_bounds__(256) void cvt4(const float* __restrict__ a,
                                            const float* __restrict__ b,
                                            const float* __restrict__ c,
                                            const float* __restrict__ dd,
                                            bf16* __restrict__ oa,
                                            bf16* __restrict__ ob,
                                            bf16* __restrict__ oc,
                                            bf16* __restrict__ od) {
  const int z = blockIdx.y;
  const float* s = (z == 0) ? a : (z == 1) ? b : (z == 2) ? c : dd;
  bf16* d = (z == 0) ? oa : (z == 1) ? ob : (z == 2) ? oc : od;
  const int i = blockIdx.x * 256 + threadIdx.x;
  float4 f = reinterpret_cast<const float4*>(s)[i];
  bf16x4 o = {(bf16)f.x, (bf16)f.y, (bf16)f.z, (bf16)f.w};
  reinterpret_cast<bf16x4*>(d)[i] = o;
}

// ---------------------------------------------------------------------------
// Proven GEMM core: 128x128 tile, BK=32, global_load_lds width=16,
// unswizzled LDS, 16x16x32 bf16 MFMA. C = A[M,1024] @ W[1024,1024]^T.
__device__ __forceinline__ void gemm_core(const bf16* __restrict__ A,
                                          const bf16* __restrict__ B,
                                          bf16* As, bf16* Bs, int t,
                                          int m0, int n0, f32x4 acc[4][4]) {
  constexpr int K = 1024;
  const int lane = t & 63;
  const int wave = t >> 6;
  const int wm = wave >> 1, wn = wave & 1;
  const int r16 = lane & 15, quad = lane >> 4;

  for (int k0 = 0; k0 < K; k0 += 32) {
    __syncthreads();
#pragma unroll
    for (int hh = 0; hh < 2; ++hh) {
      const int c = t + hh * 256;
      const int row = c >> 2, kk = (c & 3) * 8;
      gld_lds16(A + (size_t)(m0 + row) * K + k0 + kk, As + c * 8);
      gld_lds16(B + (size_t)(n0 + row) * K + k0 + kk, Bs + c * 8);
    }
    __syncthreads();
    bf16x8 af[4], bfr[4];
#pragma unroll
    for (int i = 0; i < 4; ++i)
      af[i] = *(const bf16x8*)&As[(wm * 64 + i * 16 + r16) * 32 + quad * 8];
#pragma unroll
    for (int i = 0; i < 4; ++i)
      bfr[i] = *(const bf16x8*)&Bs[(wn * 64 + i * 16 + r16) * 32 + quad * 8];
#pragma unroll
    for (int mi = 0; mi < 4; ++mi)
#pragma unroll
      for (int ni = 0; ni < 4; ++ni)
        acc[mi][ni] = __builtin_amdgcn_mfma_f32_16x16x32_bf16(af[mi], bfr[ni],
                                                              acc[mi][ni], 0, 0, 0);
  }
}

// Fused Q/K/V projections. Work remapped XCD-aware: the 8 n-blocks sharing
// one A-panel (same z,y) are co-XCD. Q,K -> [B,H,S,64] (Q scaled);
// V -> [B,H,64,S] transposed.
__global__ __launch_bounds__(256) void gemm_qkv(
    const bf16* __restrict__ qb, const bf16* __restrict__ kb,
    const bf16* __restrict__ vb, const bf16* __restrict__ Wqb,
    const bf16* __restrict__ Wkb, const bf16* __restrict__ Wvb,
    const float* __restrict__ bq, const float* __restrict__ bk,
    const float* __restrict__ bv, bf16* __restrict__ Qp,
    bf16* __restrict__ Kp, bf16* __restrict__ VTt, float qscale) {
  __shared__ alignas(16) bf16 As[128 * 32];
  __shared__ alignas(16) bf16 Bs[128 * 32];

  // XCD-aware bijective swizzle over all 1536 blocks (= 8 XCDs * 192).
  const int lin = blockIdx.x + (blockIdx.y << 3) + (blockIdx.z << 9);
  const int w = ((lin & 7) * 192) + (lin >> 3);
  const int which = w >> 9;          // 0..2
  const int rem = w & 511;
  const int m0 = (rem >> 3) * 128;   // y' * 128
  const int n0 = (rem & 7) * 128;    // x' * 128

  const bf16* A = (which == 0) ? qb : (which == 1) ? kb : vb;
  const bf16* W = (which == 0) ? Wqb : (which == 1) ? Wkb : Wvb;
  const float* bias = (which == 0) ? bq : (which == 1) ? bk : bv;
  const float oscale = (which == 0) ? qscale : 1.0f;
  bf16* Cb = (which == 0) ? Qp : (which == 1) ? Kp : VTt;

  const int t = threadIdx.x;
  f32x4 acc[4][4] = {};
  gemm_core(A, W, As, Bs, t, m0, n0, acc);

  const int lane = t & 63, wave = t >> 6;
  const int wm = wave >> 1, wn = wave & 1;
  const int r16 = lane & 15, quad = lane >> 4;
#pragma unroll
  for (int mi = 0; mi < 4; ++mi) {
    const int m = m0 + wm * 64 + mi * 16 + quad * 4;
#pragma unroll
    for (int ni = 0; ni < 4; ++ni) {
      const int n = n0 + wn * 64 + ni * 16 + r16;
      const float bv_ = bias[n];
      const int h = n >> 6, dh = n & 63;
      if (which < 2) {
#pragma unroll
        for (int i = 0; i < 4; ++i) {
          const int mm = m + i;
          const int b = mm >> 11, s = mm & 2047;
          Cb[(((size_t)(b * 16 + h)) * 2048 + s) * 64 + dh] =
              (bf16)((acc[mi][ni][i] + bv_) * oscale);
        }
      } else {
        const int b = m >> 11, s = m & 2047;
        bf16x4 pk;
#pragma unroll
        for (int i = 0; i < 4; ++i) pk[i] = (bf16)(acc[mi][ni][i] + bv_);
        *(bf16x4*)&Cb[(((size_t)(b * 16 + h)) * 64 + dh) * 2048 + s] = pk;
      }
    }
  }
}

// Final projection: fp32 out + bias. XCD swizzle (512 = 8*64).
__global__ __launch_bounds__(256) void gemm_out(const bf16* __restrict__ A,
                                                const bf16* __restrict__ W,
                                                const float* __restrict__ bias,
                                                float* __restrict__ Cf) {
  __shared__ alignas(16) bf16 As[128 * 32];
  __shared__ alignas(16) bf16 Bs[128 * 32];
  const int t = threadIdx.x;

  const int lin = blockIdx.x + (blockIdx.y << 3);
  const int w = ((lin & 7) << 6) + (lin >> 3);
  const int m0 = (w >> 3) * 128;
  const int n0 = (w & 7) * 128;

  f32x4 acc[4][4] = {};
  gemm_core(A, W, As, Bs, t, m0, n0, acc);

  const int lane = t & 63, wave = t >> 6;
  const int wm = wave >> 1, wn = wave & 1;
  const int r16 = lane & 15, quad = lane >> 4;
#pragma unroll
  for (int mi = 0; mi < 4; ++mi) {
    const int m = m0 + wm * 64 + mi * 16 + quad * 4;
#pragma unroll
    for (int ni = 0; ni < 4; ++ni) {
      const int n = n0 + wn * 64 + ni * 16 + r16;
      const float bv_ = bias[n];
#pragma unroll
      for (int i = 0; i < 4; ++i)
        Cf[(size_t)(m + i) * 1024 + n] = acc[mi][ni][i] + bv_;
    }
  }
}

// ---------------------------------------------------------------------------
// Flash attention, S^T formulation, no-max softmax, P redistributed via
// permlane swap BUILTINS (VALU pipe) instead of LDS. grid = (S/128, B*H),
// 256 threads (4 waves x 32 q). K/V LDS stride 72 (as R6/R13).
// Per (nq,ks), with A = P dwords of mi=2ks, B = of mi=2ks+1 (j=0,1 pairs):
//   r = permlane32_swap(A,B): r[0]={A_lo,B_lo}, r[1]={A_hi,B_hi}
//   s = permlane16_swap(r[0],r[1]): s[0]=f0={A@q0,A@q2,B@q0,B@q2},
//                                   s[1]=f2={A@q1,A@q3,B@q1,B@q3}
// Fragment = {f0,f1,f2,f3} (f1/f3 from the j=1 dwords). Target layout
// verified identical to R10's harness-passing shfl redistribution.
__global__ __launch_bounds__(256) void attn_fwd(const bf16* __restrict__ Qp,
                                                const bf16* __restrict__ Kp,
                                                const bf16* __restrict__ VT,
                                                bf16* __restrict__ AO) {
  __shared__ alignas(16) bf16 Ks[64 * 72];   // [kv][dk], stride 72
  __shared__ alignas(16) bf16 Vs[64 * 72];   // [dk][kv], stride 72
  __shared__ float Lr[128];                  // per-q row-sum scratch
  const int t = threadIdx.x, lane = t & 63, wave = t >> 6;
  const int r16 = lane & 15, quad = lane >> 4;
  const int bh = blockIdx.y;
  const int q0 = blockIdx.x * 128;
  const int qw = wave * 32;  // wave's local q base
  const bf16* Qb = Qp + (size_t)bh * (2048 * 64);
  const bf16* Kb = Kp + (size_t)bh * (2048 * 64);
  const bf16* Vb = VT + (size_t)bh * (64 * 2048);

  // Q fragments from global, used as B-operand (n=q=lane&15, k=dk=quad*8+j).
  bf16x8 qf[2][2];
#pragma unroll
  for (int nq = 0; nq < 2; ++nq)
#pragma unroll
    for (int ks = 0; ks < 2; ++ks)
      qf[nq][ks] = *(const bf16x8*)&Qb[(size_t)(q0 + qw + nq * 16 + r16) * 64 +
                                       ks * 32 + quad * 8];

  // staging chunks: c = 2t, 2t+1 over 512 chunks
  const int c0 = t * 2, c1 = t * 2 + 1;
  const int kr0 = c0 >> 3, kc0 = (c0 & 7) * 8;
  const int kr1 = c1 >> 3, kc1 = (c1 & 7) * 8;

  bf16x8 kreg0 = *(const bf16x8*)(Kb + (size_t)kr0 * 64 + kc0);
  bf16x8 kreg1 = *(const bf16x8*)(Kb + (size_t)kr1 * 64 + kc1);
  bf16x8 vreg0 = *(const bf16x8*)(Vb + (size_t)kr0 * 2048 + kc0);
  bf16x8 vreg1 = *(const bf16x8*)(Vb + (size_t)kr1 * 2048 + kc1);

  f32x4 o[2][4] = {};
  float lrow[2] = {0.f, 0.f};  // per-lane partial sum for q = qw + nq*16 + r16

  for (int kv0 = 0; kv0 < 2048; kv0 += 64) {
    __syncthreads();
    *(bf16x8*)&Ks[kr0 * 72 + kc0] = kreg0;
    *(bf16x8*)&Ks[kr1 * 72 + kc1] = kreg1;
    *(bf16x8*)&Vs[kr0 * 72 + kc0] = vreg0;
    *(bf16x8*)&Vs[kr1 * 72 + kc1] = vreg1;
    __syncthreads();

    if (kv0 + 64 < 2048) {
      const int nx = kv0 + 64;
      kreg0 = *(const bf16x8*)(Kb + (size_t)(nx + kr0) * 64 + kc0);
      kreg1 = *(const bf16x8*)(Kb + (size_t)(nx + kr1) * 64 + kc1);
      vreg0 = *(const bf16x8*)(Vb + (size_t)kr0 * 2048 + nx + kc0);
      vreg1 = *(const bf16x8*)(Vb + (size_t)kr1 * 2048 + nx + kc1);
    }

    // K fragments (A-operand: m=kv=lane&15 per 16-row subtile, k=dk).
    bf16x8 kf[4][2];
#pragma unroll
    for (int mi = 0; mi < 4; ++mi) {
      kf[mi][0] = *(const bf16x8*)&Ks[(mi * 16 + r16) * 72 + quad * 8];
      kf[mi][1] = *(const bf16x8*)&Ks[(mi * 16 + r16) * 72 + 32 + quad * 8];
    }

    // QK^T + exp + permlane P redistribution (VALU pipe, no LDS)
    bf16x8 pfr[2][2];  // [nq][ks] PV A-operand fragments
#pragma unroll
    for (int nq = 0; nq < 2; ++nq) {
      unsigned pk_i[4][2];  // per mi: P dwords (bf16x4 as 2 dwords)
#pragma unroll
      for (int mi = 0; mi < 4; ++mi) {
        f32x4 z = {};
        z = __builtin_amdgcn_mfma_f32_16x16x32_bf16(kf[mi][0], qf[nq][0], z, 0, 0, 0);
        z = __builtin_amdgcn_mfma_f32_16x16x32_bf16(kf[mi][1], qf[nq][1], z, 0, 0, 0);
        bf16x4 pk;
#pragma unroll
        for (int i = 0; i < 4; ++i) {
          const float p = __builtin_amdgcn_exp2f(z[i]);
          lrow[nq] += p;
          pk[i] = (bf16)p;
        }
        const i32x2 pp = __builtin_bit_cast(i32x2, pk);
        pk_i[mi][0] = (unsigned)pp[0];
        pk_i[mi][1] = (unsigned)pp[1];
      }
#pragma unroll
      for (int ks = 0; ks < 2; ++ks) {
        const u32x2 r0 = __builtin_amdgcn_permlane32_swap(
            pk_i[2 * ks][0], pk_i[2 * ks + 1][0], false, false);
        const u32x2 s0 = __builtin_amdgcn_permlane16_swap(r0[0], r0[1], false, false);
        const u32x2 r1 = __builtin_amdgcn_permlane32_swap(
            pk_i[2 * ks][1], pk_i[2 * ks + 1][1], false, false);
        const u32x2 s1 = __builtin_amdgcn_permlane16_swap(r1[0], r1[1], false, false);
        i32x4 f;
        f[0] = (int)s0[0];  // f0: dword chunk 16ks+4q
        f[1] = (int)s1[0];  // f1: +1
        f[2] = (int)s0[1];  // f2: +2
        f[3] = (int)s1[1];  // f3: +3
        pfr[nq][ks] = __builtin_bit_cast(bf16x8, f);
      }
    }

    // O += P V  (A-fragments from regs, V from Vs)
#pragma unroll
    for (int ks = 0; ks < 2; ++ks) {
#pragma unroll
      for (int ni = 0; ni < 4; ++ni) {
        bf16x8 vf = *(const bf16x8*)&Vs[(ni * 16 + r16) * 72 + ks * 32 + quad * 8];
#pragma unroll
        for (int nq = 0; nq < 2; ++nq)
          o[nq][ni] = __builtin_amdgcn_mfma_f32_16x16x32_bf16(pfr[nq][ks], vf, o[nq][ni], 0, 0, 0);
      }
    }
  }

  // move l from softmax-lanes (q = qw+nq*16+r16) to epilogue-lanes via LDS
#pragma unroll
  for (int nq = 0; nq < 2; ++nq) {
    float s = lrow[nq];
    s += __shfl_xor(s, 16);
    s += __shfl_xor(s, 32);  // sum across quads -> full row sum
    if (quad == 0) Lr[qw + nq * 16 + r16] = s;
  }
  f32x4 lr[2];
#pragma unroll
  for (int mi = 0; mi < 2; ++mi)
    lr[mi] = *(const f32x4*)&Lr[qw + mi * 16 + quad * 4];  // same-wave RAW

  const int b = bh >> 4, h = bh & 15;
#pragma unroll
  for (int mi = 0; mi < 2; ++mi)
#pragma unroll
    for (int i = 0; i < 4; ++i) {
      const float rl = 1.0f / lr[mi][i];
      const int sq = q0 + qw + mi * 16 + quad * 4 + i;
      const size_t base = ((size_t)(b * 2048 + sq)) * 1024 + h * 64;
#pragma unroll
      for (int ni = 0; ni < 4; ++ni)
        AO[base + ni * 16 + r16] = (bf16)(o[mi][ni][i] * rl);
    }
}

// ---------------------------------------------------------------------------
extern "C" void kernel_launch(void* const* d_in, const int* in_sizes, int n_in,
                              void* d_out, int out_size, void* d_ws, size_t ws_size,
                              hipStream_t stream) {
  const float* q  = (const float*)d_in[0];
  const float* k  = (const float*)d_in[1];
  const float* v  = (const float*)d_in[2];
  const float* Wq = (const float*)d_in[3];
  const float* bq = (const float*)d_in[4];
  const float* Wk = (const float*)d_in[5];
  const float* bk = (const float*)d_in[6];
  const float* Wv = (const float*)d_in[7];
  const float* bv = (const float*)d_in[8];
  const float* Wo = (const float*)d_in[9];
  const float* bo = (const float*)d_in[10];

  char* ws = (char*)d_ws;
  const size_t MB = 1ull << 20;
  bf16* qb  = (bf16*)(ws + 0);         // 16 MB (reused as AO after Q-proj)
  bf16* kb  = (bf16*)(ws + 16 * MB);
  bf16* vb  = (bf16*)(ws + 32 * MB);
  bf16* Wqb = (bf16*)(ws + 48 * MB);
  bf16* Wkb = (bf16*)(ws + 50 * MB);
  bf16* Wvb = (bf16*)(ws + 52 * MB);
  bf16* Wob = (bf16*)(ws + 54 * MB);
  bf16* Qp  = (bf16*)(ws + 56 * MB);   // [B,H,S,64]
  bf16* Kp  = (bf16*)(ws + 72 * MB);   // [B,H,S,64]
  bf16* VTt = (bf16*)(ws + 88 * MB);   // [B,H,64,S]
  bf16* AO  = qb;

  cvt3<<<dim3(8192, 3), 256, 0, stream>>>(q, k, v, qb, kb, vb);
  cvt4<<<dim3(1024, 4), 256, 0, stream>>>(Wq, Wk, Wv, Wo, Wqb, Wkb, Wvb, Wob);

  const float qscale = 0.125f * 1.44269504088896340736f;  // 1/sqrt(64) * log2(e)
  gemm_qkv<<<dim3(8, 64, 3), 256, 0, stream>>>(qb, kb, vb, Wqb, Wkb, Wvb,
                                               bq, bk, bv, Qp, Kp, VTt, qscale);

  attn_fwd<<<dim3(16, 64), 256, 0, stream>>>(Qp, Kp, VTt, AO);

  gemm_out<<<dim3(8, 64), 256, 0, stream>>>(AO, Wob, bo, (float*)d_out);
}